// Round 7
// baseline (390.010 us; speedup 1.0000x reference)
//
#include <hip/hip_runtime.h>
#include <hip/hip_bf16.h>

#define HW 512
#define CH 3

typedef float v4f __attribute__((ext_vector_type(4)));

// 2 output rows x 4 px x 3 oc = 24 accumulators/thread. Target: <=64 VGPR
// (launch_bounds 8 waves/EU) to double occupancy vs R3's 108-VGPR kernel.
// Weights wave-uniform (readfirstlane'd expert) -> SGPRs.
__global__ __launch_bounds__(256, 8) void moe_conv3x3_kernel(
    const float* __restrict__ img,   // [B,3,512,512]
    const float* __restrict__ Wt,    // [E,3,3,3,3] OIHW per expert
    const float* __restrict__ bias,  // [E,3]
    const int*   __restrict__ alloc, // [B]
    float*       __restrict__ out)   // [B,3,512,512]
{
    const int b = blockIdx.y;
    int e = alloc[b];
    e = __builtin_amdgcn_readfirstlane(e);   // wave-uniform -> s_loads

    const float* we = Wt + (size_t)e * (CH * CH * 9);

    float bv[CH];
#pragma unroll
    for (int oc = 0; oc < CH; ++oc) bv[oc] = bias[(size_t)e * CH + oc];

    const int idx = blockIdx.x * 256 + threadIdx.x;  // 0..32767
    const int w4  = (idx & 127) * 4;                 // 0..508 step 4
    const int hb  = (idx >> 7) * 2;                  // 0..510 step 2

    const float* inb = img + (size_t)b * CH * HW * HW;

    float acc[CH][2][4];
#pragma unroll
    for (int oc = 0; oc < CH; ++oc)
#pragma unroll
        for (int r = 0; r < 2; ++r)
#pragma unroll
            for (int j = 0; j < 4; ++j) acc[oc][r][j] = bv[oc];

#pragma unroll
    for (int ci = 0; ci < CH; ++ci) {
        const float* inc = inb + (size_t)ci * HW * HW;

        float wk[CH][3][3];  // wave-uniform -> scalar regs
#pragma unroll
        for (int oc = 0; oc < CH; ++oc)
#pragma unroll
            for (int kh = 0; kh < 3; ++kh)
#pragma unroll
                for (int kw = 0; kw < 3; ++kw)
                    wk[oc][kh][kw] = we[((oc * CH + ci) * 3 + kh) * 3 + kw];

#pragma unroll
        for (int ri = 0; ri < 4; ++ri) {            // input rows hb-1 .. hb+2
            const int hr = hb + ri - 1;
            float row[6];
            if (hr >= 0 && hr < HW) {               // wave-uniform branch
                const float* rsrc = inc + (size_t)hr * HW + w4;
                const v4f v = *(const v4f*)rsrc;
                row[1] = v.x; row[2] = v.y; row[3] = v.z; row[4] = v.w;
                row[0] = (w4 > 0)      ? rsrc[-1] : 0.0f;
                row[5] = (w4 < HW - 4) ? rsrc[4]  : 0.0f;
            } else {
#pragma unroll
                for (int j = 0; j < 6; ++j) row[j] = 0.0f;
            }

            // input row ri -> output rows r with kh = ri - r in [0,2]
#pragma unroll
            for (int r = 0; r < 2; ++r) {
                const int kh = ri - r;
                if (kh >= 0 && kh < 3) {
#pragma unroll
                    for (int kw = 0; kw < 3; ++kw) {
#pragma unroll
                        for (int oc = 0; oc < CH; ++oc) {
                            const float wv = wk[oc][kh][kw];
#pragma unroll
                            for (int j = 0; j < 4; ++j)
                                acc[oc][r][j] = fmaf(row[j + kw], wv, acc[oc][r][j]);
                        }
                    }
                }
            }
        }
    }

    float* ob = out + (size_t)b * CH * HW * HW + (size_t)hb * HW + w4;
#pragma unroll
    for (int oc = 0; oc < CH; ++oc) {
#pragma unroll
        for (int r = 0; r < 2; ++r) {
            v4f v;
            v.x = acc[oc][r][0]; v.y = acc[oc][r][1];
            v.z = acc[oc][r][2]; v.w = acc[oc][r][3];
            *(v4f*)(ob + (size_t)oc * HW * HW + (size_t)r * HW) = v;
        }
    }
}

extern "C" void kernel_launch(void* const* d_in, const int* in_sizes, int n_in,
                              void* d_out, int out_size, void* d_ws, size_t ws_size,
                              hipStream_t stream) {
    const float* img   = (const float*)d_in[0];  // [32,3,512,512]
    const float* Wt    = (const float*)d_in[1];  // [64,3,3,3,3]
    const float* bias  = (const float*)d_in[2];  // [64,3]
    const int*   alloc = (const int*)d_in[3];    // [32]
    float*       out   = (float*)d_out;          // [32,3,512,512]

    const int B = in_sizes[3];                   // 32
    dim3 grid(128, B);                           // 128 blocks x 256 thr = 32768 thr/sample
    dim3 block(256);
    moe_conv3x3_kernel<<<grid, block, 0, stream>>>(img, Wt, bias, alloc, out);
}

// Round 8
// 57.554 us; speedup vs baseline: 6.7765x; 6.7765x over previous
//
#include <hip/hip_runtime.h>
#include <hip/hip_bf16.h>

#define HW 512
#define CH 3

typedef float v4f __attribute__((ext_vector_type(4)));

// R3 tile (4 rows x 4 px x 3 oc, 48 acc, 41 us) with a BRANCH-FREE inner
// body: row bounds handled by clamped address + uniform zero-mask multiply
// instead of an if — lets the scheduler hoist loads across rows/channels
// for deeper MLP. Halo scalars stay lane-predicated (masked, no OOB).
__global__ __launch_bounds__(256) void moe_conv3x3_kernel(
    const float* __restrict__ img,   // [B,3,512,512]
    const float* __restrict__ Wt,    // [E,3,3,3,3] OIHW per expert
    const float* __restrict__ bias,  // [E,3]
    const int*   __restrict__ alloc, // [B]
    float*       __restrict__ out)   // [B,3,512,512]
{
    const int b = blockIdx.y;
    int e = alloc[b];
    e = __builtin_amdgcn_readfirstlane(e);   // wave-uniform -> s_loads

    const float* we = Wt + (size_t)e * (CH * CH * 9);

    float bv[CH];
#pragma unroll
    for (int oc = 0; oc < CH; ++oc) bv[oc] = bias[(size_t)e * CH + oc];

    const int idx = blockIdx.x * 256 + threadIdx.x;  // 0..16383
    const int w4  = (idx & 127) * 4;                 // 0..508 step 4
    const int hb  = (idx >> 7) * 4;                  // 0..508 step 4 (wave-uniform)

    const float* inb = img + (size_t)b * CH * HW * HW;

    float acc[CH][4][4];
#pragma unroll
    for (int oc = 0; oc < CH; ++oc)
#pragma unroll
        for (int r = 0; r < 4; ++r)
#pragma unroll
            for (int j = 0; j < 4; ++j) acc[oc][r][j] = bv[oc];

#pragma unroll
    for (int ci = 0; ci < CH; ++ci) {
        const float* inc = inb + (size_t)ci * HW * HW;

        float wk[CH][3][3];  // wave-uniform -> scalar regs
#pragma unroll
        for (int oc = 0; oc < CH; ++oc)
#pragma unroll
            for (int kh = 0; kh < 3; ++kh)
#pragma unroll
                for (int kw = 0; kw < 3; ++kw)
                    wk[oc][kh][kw] = we[((oc * CH + ci) * 3 + kh) * 3 + kw];

#pragma unroll
        for (int ri = 0; ri < 6; ++ri) {            // input rows hb-1 .. hb+4
            const int hr  = hb + ri - 1;
            const int hrc = hr < 0 ? 0 : (hr > HW - 1 ? HW - 1 : hr);
            const float vm = (hr == hrc) ? 1.0f : 0.0f;   // wave-uniform mask
            const float* rsrc = inc + (size_t)hrc * HW + w4;

            const v4f v = *(const v4f*)rsrc;              // unconditional
            float row[6];
            row[1] = v.x * vm; row[2] = v.y * vm;
            row[3] = v.z * vm; row[4] = v.w * vm;
            row[0] = (w4 > 0)      ? rsrc[-1] * vm : 0.0f;  // lane-masked
            row[5] = (w4 < HW - 4) ? rsrc[4]  * vm : 0.0f;  // lane-masked

            // input row ri -> output rows r with kh = ri - r in [0,2]
#pragma unroll
            for (int r = 0; r < 4; ++r) {
                const int kh = ri - r;
                if (kh >= 0 && kh < 3) {                  // compile-time
#pragma unroll
                    for (int kw = 0; kw < 3; ++kw) {
#pragma unroll
                        for (int oc = 0; oc < CH; ++oc) {
                            const float wv = wk[oc][kh][kw];
#pragma unroll
                            for (int j = 0; j < 4; ++j)
                                acc[oc][r][j] = fmaf(row[j + kw], wv, acc[oc][r][j]);
                        }
                    }
                }
            }
        }
    }

    float* ob = out + (size_t)b * CH * HW * HW + (size_t)hb * HW + w4;
#pragma unroll
    for (int oc = 0; oc < CH; ++oc) {
#pragma unroll
        for (int r = 0; r < 4; ++r) {
            v4f v;
            v.x = acc[oc][r][0]; v.y = acc[oc][r][1];
            v.z = acc[oc][r][2]; v.w = acc[oc][r][3];
            *(v4f*)(ob + (size_t)oc * HW * HW + (size_t)r * HW) = v;
        }
    }
}

extern "C" void kernel_launch(void* const* d_in, const int* in_sizes, int n_in,
                              void* d_out, int out_size, void* d_ws, size_t ws_size,
                              hipStream_t stream) {
    const float* img   = (const float*)d_in[0];  // [32,3,512,512]
    const float* Wt    = (const float*)d_in[1];  // [64,3,3,3,3]
    const float* bias  = (const float*)d_in[2];  // [64,3]
    const int*   alloc = (const int*)d_in[3];    // [32]
    float*       out   = (float*)d_out;          // [32,3,512,512]

    const int B = in_sizes[3];                   // 32
    dim3 grid(64, B);                            // 64 blocks x 256 thr
    dim3 block(256);
    moe_conv3x3_kernel<<<grid, block, 0, stream>>>(img, Wt, bias, alloc, out);
}

// Round 9
// 50.582 us; speedup vs baseline: 7.7105x; 1.1378x over previous
//
#include <hip/hip_runtime.h>
#include <hip/hip_bf16.h>

#define HW 512
#define CH 3

typedef float v4f __attribute__((ext_vector_type(4)));

// R3 tile (4 rows x 4 px x 3 oc = 48 acc; 41 us baseline) with a phase-split
// schedule per input channel: issue ALL 18 row loads first (6x float4 + 12
// halo scalars), then run all FMAs. Goal: 18-deep VMEM burst per wave
// (vs ~3 in R3's load->FMA->load interleave) to hide HBM latency.
__global__ __launch_bounds__(256) void moe_conv3x3_kernel(
    const float* __restrict__ img,   // [B,3,512,512]
    const float* __restrict__ Wt,    // [E,3,3,3,3] OIHW per expert
    const float* __restrict__ bias,  // [E,3]
    const int*   __restrict__ alloc, // [B]
    float*       __restrict__ out)   // [B,3,512,512]
{
    const int b = blockIdx.y;
    int e = alloc[b];
    e = __builtin_amdgcn_readfirstlane(e);   // wave-uniform -> s_loads

    const float* we = Wt + (size_t)e * (CH * CH * 9);

    float bv[CH];
#pragma unroll
    for (int oc = 0; oc < CH; ++oc) bv[oc] = bias[(size_t)e * CH + oc];

    const int idx = blockIdx.x * 256 + threadIdx.x;  // 0..16383
    const int w4  = (idx & 127) * 4;                 // 0..508 step 4
    const int hb  = (idx >> 7) * 4;                  // 0..508 step 4 (wave-uniform)

    const float* inb = img + (size_t)b * CH * HW * HW;

    float acc[CH][4][4];
#pragma unroll
    for (int oc = 0; oc < CH; ++oc)
#pragma unroll
        for (int r = 0; r < 4; ++r)
#pragma unroll
            for (int j = 0; j < 4; ++j) acc[oc][r][j] = bv[oc];

#pragma unroll
    for (int ci = 0; ci < CH; ++ci) {
        const float* inc = inb + (size_t)ci * HW * HW;

        float wk[CH][3][3];  // wave-uniform -> scalar regs
#pragma unroll
        for (int oc = 0; oc < CH; ++oc)
#pragma unroll
            for (int kh = 0; kh < 3; ++kh)
#pragma unroll
                for (int kw = 0; kw < 3; ++kw)
                    wk[oc][kh][kw] = we[((oc * CH + ci) * 3 + kh) * 3 + kw];

        // ---- phase 1: issue all 18 loads for this channel ----
        float rows[6][6];
#pragma unroll
        for (int ri = 0; ri < 6; ++ri) {            // input rows hb-1 .. hb+4
            const int hr = hb + ri - 1;
            if (hr >= 0 && hr < HW) {               // wave-uniform, rarely false
                const float* rsrc = inc + (size_t)hr * HW + w4;
                const v4f v = *(const v4f*)rsrc;
                rows[ri][1] = v.x; rows[ri][2] = v.y;
                rows[ri][3] = v.z; rows[ri][4] = v.w;
                rows[ri][0] = (w4 > 0)      ? rsrc[-1] : 0.0f;
                rows[ri][5] = (w4 < HW - 4) ? rsrc[4]  : 0.0f;
            } else {
#pragma unroll
                for (int j = 0; j < 6; ++j) rows[ri][j] = 0.0f;
            }
        }

        // ---- phase 2: all FMAs for this channel ----
#pragma unroll
        for (int ri = 0; ri < 6; ++ri) {
#pragma unroll
            for (int r = 0; r < 4; ++r) {
                const int kh = ri - r;
                if (kh >= 0 && kh < 3) {            // compile-time
#pragma unroll
                    for (int kw = 0; kw < 3; ++kw) {
#pragma unroll
                        for (int oc = 0; oc < CH; ++oc) {
                            const float wv = wk[oc][kh][kw];
#pragma unroll
                            for (int j = 0; j < 4; ++j)
                                acc[oc][r][j] = fmaf(rows[ri][j + kw], wv, acc[oc][r][j]);
                        }
                    }
                }
            }
        }
    }

    float* ob = out + (size_t)b * CH * HW * HW + (size_t)hb * HW + w4;
#pragma unroll
    for (int oc = 0; oc < CH; ++oc) {
#pragma unroll
        for (int r = 0; r < 4; ++r) {
            v4f v;
            v.x = acc[oc][r][0]; v.y = acc[oc][r][1];
            v.z = acc[oc][r][2]; v.w = acc[oc][r][3];
            *(v4f*)(ob + (size_t)oc * HW * HW + (size_t)r * HW) = v;
        }
    }
}

extern "C" void kernel_launch(void* const* d_in, const int* in_sizes, int n_in,
                              void* d_out, int out_size, void* d_ws, size_t ws_size,
                              hipStream_t stream) {
    const float* img   = (const float*)d_in[0];  // [32,3,512,512]
    const float* Wt    = (const float*)d_in[1];  // [64,3,3,3,3]
    const float* bias  = (const float*)d_in[2];  // [64,3]
    const int*   alloc = (const int*)d_in[3];    // [32]
    float*       out   = (float*)d_out;          // [32,3,512,512]

    const int B = in_sizes[3];                   // 32
    dim3 grid(64, B);                            // 64 blocks x 256 thr
    dim3 block(256);
    moe_conv3x3_kernel<<<grid, block, 0, stream>>>(img, Wt, bias, alloc, out);
}

// Round 10
// 50.305 us; speedup vs baseline: 7.7529x; 1.0055x over previous
//
#include <hip/hip_runtime.h>
#include <hip/hip_bf16.h>

#define HW 512
#define CH 3
#define HT 8          // output rows per block
#define NROWS 10      // staged input rows (HT+2)
#define RSTRIDE 520   // floats per LDS row slot: [0..2 pad][3 zero][4..515 data][516 zero][517..519 pad]

typedef float v4f __attribute__((ext_vector_type(4)));

// LDS-staged band conv: block = 512 thr (8 waves) owns 8 rows x 512 px x 3 oc
// of one sample. 10 input rows x 3 ch staged via global_load_lds (width 16,
// 1KB-contiguous DMA chunks, LDS dest = wave-uniform base + lane*16).
// Halos read from LDS (zero pad columns) -> no scalar VMEM gathers at all.
__global__ __launch_bounds__(512) void moe_conv3x3_kernel(
    const float* __restrict__ img,   // [B,3,512,512]
    const float* __restrict__ Wt,    // [E,3,3,3,3] OIHW per expert
    const float* __restrict__ bias,  // [E,3]
    const int*   __restrict__ alloc, // [B]
    float*       __restrict__ out)   // [B,3,512,512]
{
    __shared__ float lds[CH][NROWS][RSTRIDE];   // 62400 B

    const int band = blockIdx.x;     // 0..63
    const int b    = blockIdx.y;     // sample
    const int hb   = band * HT;
    const int tid  = threadIdx.x;
    const int lane = tid & 63;
    const int wid  = tid >> 6;       // 0..7

    int e = alloc[b];
    e = __builtin_amdgcn_readfirstlane(e);      // wave-uniform -> s_loads
    const float* we = Wt + (size_t)e * (CH * CH * 9);

    // zero halo columns once (DMA never touches slots 3 / 516)
    if (tid < CH * NROWS) {
        const int ci = tid / NROWS, r = tid % NROWS;
        lds[ci][r][3]   = 0.0f;
        lds[ci][r][516] = 0.0f;
    }

    // ---- stage: 60 chunks (ci, row, half) of 256 floats each ----
    const float* inb = img + (size_t)b * CH * HW * HW;
#pragma unroll
    for (int k = 0; k < 8; ++k) {
        const int c = wid * 8 + k;               // wave-uniform
        if (c < CH * NROWS * 2) {
            const int ci   = c / (NROWS * 2);
            const int r10  = (c % (NROWS * 2)) / 2;
            const int half = c & 1;
            const int hr   = hb - 1 + r10;
            float* dst = &lds[ci][r10][4 + half * 256];
            if (hr >= 0 && hr < HW) {
                const float* src = inb + ((size_t)ci * HW + hr) * HW
                                       + half * 256 + lane * 4;
                __builtin_amdgcn_global_load_lds(
                    (const __attribute__((address_space(1))) void*)src,
                    (__attribute__((address_space(3))) void*)dst,
                    16, 0, 0);
            } else {
                *(v4f*)(dst + lane * 4) = (v4f)0.0f;   // OOB row -> zeros
            }
        }
    }
    __syncthreads();   // compiler drains vmcnt before s_barrier

    // ---- compute: wave w owns output row hb+w; lane l owns px 4l+{0..3} and 256+4l+{0..3} ----
    float bv[CH];
#pragma unroll
    for (int oc = 0; oc < CH; ++oc) bv[oc] = bias[(size_t)e * CH + oc];

    float acc[CH][2][4];
#pragma unroll
    for (int oc = 0; oc < CH; ++oc)
#pragma unroll
        for (int g = 0; g < 2; ++g)
#pragma unroll
            for (int j = 0; j < 4; ++j) acc[oc][g][j] = bv[oc];

    const int l4 = 4 * lane;

#pragma unroll
    for (int ci = 0; ci < CH; ++ci) {
        float wk[CH][3][3];   // wave-uniform -> scalar regs
#pragma unroll
        for (int oc = 0; oc < CH; ++oc)
#pragma unroll
            for (int kh = 0; kh < 3; ++kh)
#pragma unroll
                for (int kw = 0; kw < 3; ++kw)
                    wk[oc][kh][kw] = we[((oc * CH + ci) * 3 + kh) * 3 + kw];

#pragma unroll
        for (int kh = 0; kh < 3; ++kh) {
            const float* rowp = &lds[ci][wid + kh][0];
            const v4f va = *(const v4f*)(rowp + 4 + l4);     // px 4l..4l+3
            const float la = rowp[3 + l4];                   // px 4l-1 (or zero pad)
            const float ra = rowp[8 + l4];                   // px 4l+4
            const v4f vb = *(const v4f*)(rowp + 260 + l4);   // px 256+4l..
            const float lb = rowp[259 + l4];
            const float rb = rowp[264 + l4];

            const float ax[6] = {la, va.x, va.y, va.z, va.w, ra};
            const float bx[6] = {lb, vb.x, vb.y, vb.z, vb.w, rb};

#pragma unroll
            for (int kw = 0; kw < 3; ++kw) {
#pragma unroll
                for (int oc = 0; oc < CH; ++oc) {
                    const float wv = wk[oc][kh][kw];
#pragma unroll
                    for (int j = 0; j < 4; ++j) {
                        acc[oc][0][j] = fmaf(ax[kw + j], wv, acc[oc][0][j]);
                        acc[oc][1][j] = fmaf(bx[kw + j], wv, acc[oc][1][j]);
                    }
                }
            }
        }
    }

    // ---- store: lane-contiguous float4 (1KB per wave-instruction) ----
    const int h = hb + wid;
    float* ob = out + (size_t)b * CH * HW * HW + (size_t)h * HW;
#pragma unroll
    for (int oc = 0; oc < CH; ++oc) {
#pragma unroll
        for (int g = 0; g < 2; ++g) {
            v4f v;
            v.x = acc[oc][g][0]; v.y = acc[oc][g][1];
            v.z = acc[oc][g][2]; v.w = acc[oc][g][3];
            *(v4f*)(ob + (size_t)oc * HW * HW + g * 256 + l4) = v;
        }
    }
}

extern "C" void kernel_launch(void* const* d_in, const int* in_sizes, int n_in,
                              void* d_out, int out_size, void* d_ws, size_t ws_size,
                              hipStream_t stream) {
    const float* img   = (const float*)d_in[0];  // [32,3,512,512]
    const float* Wt    = (const float*)d_in[1];  // [64,3,3,3,3]
    const float* bias  = (const float*)d_in[2];  // [64,3]
    const int*   alloc = (const int*)d_in[3];    // [32]
    float*       out   = (float*)d_out;          // [32,3,512,512]

    const int B = in_sizes[3];                   // 32
    dim3 grid(HW / HT, B);                       // 64 bands x 32 samples
    dim3 block(512);
    moe_conv3x3_kernel<<<grid, block, 0, stream>>>(img, Wt, bias, alloc, out);
}

// Round 11
// 43.559 us; speedup vs baseline: 8.9535x; 1.1549x over previous
//
#include <hip/hip_runtime.h>
#include <hip/hip_bf16.h>

#define HW 512
#define CH 3

typedef float v4f __attribute__((ext_vector_type(4)));

// 2 output rows x 4 px x 3 oc = 24 accumulators/thread — R7's tile WITHOUT
// the forced 8-waves/EU bound (that starved the allocator to 32 VGPR and
// spilled everything). Natural allocation should land ~80 VGPR -> 6
// waves/SIMD vs R3's 4: occupancy test, properly run this time.
__global__ __launch_bounds__(256) void moe_conv3x3_kernel(
    const float* __restrict__ img,   // [B,3,512,512]
    const float* __restrict__ Wt,    // [E,3,3,3,3] OIHW per expert
    const float* __restrict__ bias,  // [E,3]
    const int*   __restrict__ alloc, // [B]
    float*       __restrict__ out)   // [B,3,512,512]
{
    const int b = blockIdx.y;
    int e = alloc[b];
    e = __builtin_amdgcn_readfirstlane(e);   // wave-uniform -> s_loads

    const float* we = Wt + (size_t)e * (CH * CH * 9);

    float bv[CH];
#pragma unroll
    for (int oc = 0; oc < CH; ++oc) bv[oc] = bias[(size_t)e * CH + oc];

    const int idx = blockIdx.x * 256 + threadIdx.x;  // 0..32767
    const int w4  = (idx & 127) * 4;                 // 0..508 step 4
    const int hb  = (idx >> 7) * 2;                  // 0..510 step 2

    const float* inb = img + (size_t)b * CH * HW * HW;

    float acc[CH][2][4];
#pragma unroll
    for (int oc = 0; oc < CH; ++oc)
#pragma unroll
        for (int r = 0; r < 2; ++r)
#pragma unroll
            for (int j = 0; j < 4; ++j) acc[oc][r][j] = bv[oc];

#pragma unroll
    for (int ci = 0; ci < CH; ++ci) {
        const float* inc = inb + (size_t)ci * HW * HW;

        float wk[CH][3][3];  // wave-uniform -> scalar regs
#pragma unroll
        for (int oc = 0; oc < CH; ++oc)
#pragma unroll
            for (int kh = 0; kh < 3; ++kh)
#pragma unroll
                for (int kw = 0; kw < 3; ++kw)
                    wk[oc][kh][kw] = we[((oc * CH + ci) * 3 + kh) * 3 + kw];

#pragma unroll
        for (int ri = 0; ri < 4; ++ri) {            // input rows hb-1 .. hb+2
            const int hr = hb + ri - 1;
            float row[6];
            if (hr >= 0 && hr < HW) {               // wave-uniform branch
                const float* rsrc = inc + (size_t)hr * HW + w4;
                const v4f v = *(const v4f*)rsrc;
                row[1] = v.x; row[2] = v.y; row[3] = v.z; row[4] = v.w;
                row[0] = (w4 > 0)      ? rsrc[-1] : 0.0f;
                row[5] = (w4 < HW - 4) ? rsrc[4]  : 0.0f;
            } else {
#pragma unroll
                for (int j = 0; j < 6; ++j) row[j] = 0.0f;
            }

            // input row ri -> output rows r with kh = ri - r in [0,2]
#pragma unroll
            for (int r = 0; r < 2; ++r) {
                const int kh = ri - r;
                if (kh >= 0 && kh < 3) {            // compile-time
#pragma unroll
                    for (int kw = 0; kw < 3; ++kw) {
#pragma unroll
                        for (int oc = 0; oc < CH; ++oc) {
                            const float wv = wk[oc][kh][kw];
#pragma unroll
                            for (int j = 0; j < 4; ++j)
                                acc[oc][r][j] = fmaf(row[j + kw], wv, acc[oc][r][j]);
                        }
                    }
                }
            }
        }
    }

    float* ob = out + (size_t)b * CH * HW * HW + (size_t)hb * HW + w4;
#pragma unroll
    for (int oc = 0; oc < CH; ++oc) {
#pragma unroll
        for (int r = 0; r < 2; ++r) {
            v4f v;
            v.x = acc[oc][r][0]; v.y = acc[oc][r][1];
            v.z = acc[oc][r][2]; v.w = acc[oc][r][3];
            *(v4f*)(ob + (size_t)oc * HW * HW + (size_t)r * HW) = v;
        }
    }
}

extern "C" void kernel_launch(void* const* d_in, const int* in_sizes, int n_in,
                              void* d_out, int out_size, void* d_ws, size_t ws_size,
                              hipStream_t stream) {
    const float* img   = (const float*)d_in[0];  // [32,3,512,512]
    const float* Wt    = (const float*)d_in[1];  // [64,3,3,3,3]
    const float* bias  = (const float*)d_in[2];  // [64,3]
    const int*   alloc = (const int*)d_in[3];    // [32]
    float*       out   = (float*)d_out;          // [32,3,512,512]

    const int B = in_sizes[3];                   // 32
    dim3 grid(128, B);                           // 128 blocks x 256 thr = 32768 thr/sample
    dim3 block(256);
    moe_conv3x3_kernel<<<grid, block, 0, stream>>>(img, Wt, bias, alloc, out);
}